// Round 5
// baseline (65.602 us; speedup 1.0000x reference)
//
#include <hip/hip_runtime.h>

#define X_H 4096
#define X_W 128
#define BATCH 4
#define CH 128
#define TT_OUT 2048
#define FF 64
#define EPS_GN 1e-3f

typedef float f4 __attribute__((ext_vector_type(4)));
typedef float f2 __attribute__((ext_vector_type(2)));

// workspace float offsets
#define S1_OFF 0
#define SS_OFF (BATCH*TT_OUT)
#define MI_OFF (2*BATCH*TT_OUT)   // float2 per (b,t): {mu, istd}

// ---------------- kernel 1: per-(b,t) S1, SS (prep fused via LDS) ----------
// block = 256 threads: fq = tid&15 (4 f's each), tr = tid>>4 (16 t's per block)
__global__ __launch_bounds__(256) void stats_kernel(const float* __restrict__ x,
                                                    const float* __restrict__ w,
                                                    float* __restrict__ ws) {
    __shared__ float wlds[CH*9];
    __shared__ float Ml[81];
    __shared__ float Wl[9];
    int tid = threadIdx.x;
#pragma unroll
    for (int i = tid; i < CH*9; i += 256) wlds[i] = w[i];
    __syncthreads();
    if (tid < 81) {
        int j = tid / 9, k = tid % 9;
        float acc = 0.f;
#pragma unroll 8
        for (int c = 0; c < CH; ++c) acc = fmaf(wlds[c*9 + j], wlds[c*9 + k], acc);
        Ml[tid] = acc;
    } else if (tid < 90) {
        int k = tid - 81;
        float acc = 0.f;
#pragma unroll 8
        for (int c = 0; c < CH; ++c) acc += wlds[c*9 + k];
        Wl[k] = acc;
    }
    __syncthreads();

    int fq = tid & 15;
    int tr = tid >> 4;
    int gt = blockIdx.x * 16 + tr;          // b*2048 + t
    int t = gt & (TT_OUT - 1);
    int b = gt >> 11;
    const float* xb = x + (size_t)b * (X_H * X_W);

    float xr[3][9];
    int r0 = 2*t - 1;
#pragma unroll
    for (int kh = 0; kh < 3; ++kh) {
        int r = r0 + kh;
        if (r >= 0 && r < X_H) {
            const float* rp = xb + (size_t)r * X_W + 8*fq;
            f4 v0 = *(const f4*)rp;
            f4 v1 = *(const f4*)(rp + 4);
            xr[kh][0]=v0.x; xr[kh][1]=v0.y; xr[kh][2]=v0.z; xr[kh][3]=v0.w;
            xr[kh][4]=v1.x; xr[kh][5]=v1.y; xr[kh][6]=v1.z; xr[kh][7]=v1.w;
            xr[kh][8] = (fq == 15) ? 0.f : rp[8];
        } else {
#pragma unroll
            for (int k = 0; k < 9; ++k) xr[kh][k] = 0.f;
        }
    }

    float s1 = 0.f, ss = 0.f;
#pragma unroll
    for (int jf = 0; jf < 4; ++jf) {
        float tv[9];
#pragma unroll
        for (int kh = 0; kh < 3; ++kh)
#pragma unroll
            for (int kw = 0; kw < 3; ++kw)
                tv[kh*3+kw] = xr[kh][2*jf + kw];
#pragma unroll
        for (int k = 0; k < 9; ++k) s1 = fmaf(Wl[k], tv[k], s1);
#pragma unroll
        for (int j = 0; j < 9; ++j) {
            float tj = 0.f;
#pragma unroll
            for (int k = 0; k < 9; ++k) tj = fmaf(Ml[j*9+k], tv[k], tj);
            ss = fmaf(tv[j], tj, ss);
        }
    }
#pragma unroll
    for (int off = 1; off < 16; off <<= 1) {
        s1 += __shfl_xor(s1, off);
        ss += __shfl_xor(ss, off);
    }
    if (fq == 0) {
        ws[S1_OFF + gt] = s1;
        ws[SS_OFF + gt] = ss;
    }
}

// ---------------- kernel 2: cumulative scan -> {mu, istd}, float ----------
__global__ __launch_bounds__(256) void scan_kernel(float* __restrict__ ws) {
    int b = blockIdx.x;
    int tid = threadIdx.x;
    int lane = tid & 63;
    int wv = tid >> 6;
    const f4* S1v = (const f4*)(ws + S1_OFF + b*TT_OUT);
    const f4* SSv = (const f4*)(ws + SS_OFF + b*TT_OUT);
    f2* MI = (f2*)(ws + MI_OFF) + b*TT_OUT;
    __shared__ float wsum_lds[4];

    f4 a0 = S1v[tid*2], a1 = S1v[tid*2+1];
    f4 b0 = SSv[tid*2], b1 = SSv[tid*2+1];
    float s1loc[8] = {a0.x,a0.y,a0.z,a0.w,a1.x,a1.y,a1.z,a1.w};
    float ssloc[8] = {b0.x,b0.y,b0.z,b0.w,b1.x,b1.y,b1.z,b1.w};

    float v[8];
    float tot = 0.f;
#pragma unroll
    for (int i = 0; i < 8; ++i) { tot += s1loc[i]; v[i] = tot; }
    float incl = tot;
#pragma unroll
    for (int off = 1; off < 64; off <<= 1) {
        float n = __shfl_up(incl, off);
        if (lane >= off) incl += n;
    }
    if (lane == 63) wsum_lds[wv] = incl;
    __syncthreads();
    float woff = 0.f;
    for (int w2 = 0; w2 < wv; ++w2) woff += wsum_lds[w2];
    float prefix = woff + incl - tot;

    float muloc[8], v2[8];
    float tot2 = 0.f;
#pragma unroll
    for (int i = 0; i < 8; ++i) {
        int t = tid*8 + i;
        float cs = prefix + v[i];
        float cnt = (float)(t+1) * 8192.f;
        float mu = cs / cnt;
        float sq = ssloc[i] - 2.f*mu*s1loc[i] + 8192.f*mu*mu;
        muloc[i] = mu;
        tot2 += sq; v2[i] = tot2;
    }
    float incl2 = tot2;
#pragma unroll
    for (int off = 1; off < 64; off <<= 1) {
        float n = __shfl_up(incl2, off);
        if (lane >= off) incl2 += n;
    }
    __syncthreads();
    if (lane == 63) wsum_lds[wv] = incl2;
    __syncthreads();
    float woff2 = 0.f;
    for (int w2 = 0; w2 < wv; ++w2) woff2 += wsum_lds[w2];
    float prefix2 = woff2 + incl2 - tot2;
#pragma unroll
    for (int i = 0; i < 8; ++i) {
        int t = tid*8 + i;
        float cnt = (float)(t+1) * 8192.f;
        float var = (prefix2 + v2[i]) / cnt;
        f2 mi;
        mi.x = muloc[i];
        mi.y = rsqrtf(var + EPS_GN);
        MI[t] = mi;
    }
}

// ---------------- kernel 3: fused conv + norm + relu, float4 nt stores ----
#define T_TILE 16
#define CG 32
__global__ __launch_bounds__(256) void out_kernel(const float* __restrict__ x,
        const float* __restrict__ w, const float* __restrict__ scale,
        const float* __restrict__ ws, float* __restrict__ out) {
    __shared__ float wl[CG][9];
    __shared__ float sl[CG];
    int tid = threadIdx.x;
    int b = blockIdx.z;
    int c0 = blockIdx.y * CG;
    int t0 = blockIdx.x * T_TILE;
    for (int i = tid; i < CG*9; i += 256) wl[i/9][i%9] = w[c0*9 + i];
    if (tid < CG) sl[tid] = scale[c0 + tid];
    __syncthreads();

    int fq = tid & 15;          // 4 f's: f = 4*fq .. 4*fq+3
    int tr = tid >> 4;          // 0..15
    int t = t0 + tr;
    const float* xb = x + (size_t)b * (X_H * X_W);
    f2 mi = ((const f2*)(ws + MI_OFF))[b*TT_OUT + t];
    float mu = mi.x, istd = mi.y;

    float xr[3][9];
    int r0 = 2*t - 1;
#pragma unroll
    for (int kh = 0; kh < 3; ++kh) {
        int r = r0 + kh;
        if (r >= 0 && r < X_H) {
            const float* rp = xb + (size_t)r * X_W + 8*fq;
            f4 v0 = *(const f4*)rp;
            f4 v1 = *(const f4*)(rp + 4);
            xr[kh][0]=v0.x; xr[kh][1]=v0.y; xr[kh][2]=v0.z; xr[kh][3]=v0.w;
            xr[kh][4]=v1.x; xr[kh][5]=v1.y; xr[kh][6]=v1.z; xr[kh][7]=v1.w;
            xr[kh][8] = (fq == 15) ? 0.f : rp[8];
        } else {
#pragma unroll
            for (int k = 0; k < 9; ++k) xr[kh][k] = 0.f;
        }
    }

    float* ob = out + (((size_t)(b*CH + c0) * TT_OUT + t) * FF + 4*fq);
#pragma unroll
    for (int c = 0; c < CG; ++c) {
        float a  = istd * sl[c];
        float nb = -mu * a;
        f4 v;
#pragma unroll
        for (int jf = 0; jf < 4; ++jf) {
            float h = 0.f;
#pragma unroll
            for (int kh = 0; kh < 3; ++kh)
#pragma unroll
                for (int kw = 0; kw < 3; ++kw)
                    h = fmaf(wl[c][kh*3+kw], xr[kh][2*jf + kw], h);
            v[jf] = fmaxf(fmaf(h, a, nb), 0.f);
        }
        __builtin_nontemporal_store(v, (f4*)(ob + (size_t)c * (TT_OUT * FF)));
    }
}

extern "C" void kernel_launch(void* const* d_in, const int* in_sizes, int n_in,
                              void* d_out, int out_size, void* d_ws, size_t ws_size,
                              hipStream_t stream) {
    const float* x     = (const float*)d_in[0];
    const float* w     = (const float*)d_in[1];
    const float* scale = (const float*)d_in[2];
    float* out = (float*)d_out;
    float* ws  = (float*)d_ws;

    stats_kernel<<<(BATCH*TT_OUT)/16, 256, 0, stream>>>(x, w, ws);
    scan_kernel<<<BATCH, 256, 0, stream>>>(ws);
    out_kernel<<<dim3(TT_OUT/T_TILE, CH/CG, BATCH), 256, 0, stream>>>(x, w, scale, ws, out);
}

// Round 6
// 64.656 us; speedup vs baseline: 1.0146x; 1.0146x over previous
//
#include <hip/hip_runtime.h>

#define X_H 4096
#define X_W 128
#define BATCH 4
#define CH 128
#define TT_OUT 2048
#define FF 64
#define EPS_GN 1e-3f

typedef float f4 __attribute__((ext_vector_type(4)));
typedef float f2 __attribute__((ext_vector_type(2)));
typedef _Float16 h2 __attribute__((ext_vector_type(2)));

#if defined(__has_builtin)
#if __has_builtin(__builtin_amdgcn_fdot2)
#define DOT2(a, b, c) __builtin_amdgcn_fdot2((a), (b), (c), false)
#endif
#endif
#ifndef DOT2
#define DOT2(a, b, c) fmaf((float)(a).x, (float)(b).x, fmaf((float)(a).y, (float)(b).y, (c)))
#endif

// workspace float offsets
#define S1_OFF 0
#define SS_OFF (BATCH*TT_OUT)
#define MI_OFF (2*BATCH*TT_OUT)   // float2 per (b,t): {mu, istd}

// ---------------- kernel 1: per-(b,t) S1, SS (prep fused via LDS) ----------
__global__ __launch_bounds__(256) void stats_kernel(const float* __restrict__ x,
                                                    const float* __restrict__ w,
                                                    float* __restrict__ ws) {
    __shared__ float wlds[CH*9];
    __shared__ float Ml[81];
    __shared__ float Wl[9];
    int tid = threadIdx.x;
#pragma unroll
    for (int i = tid; i < CH*9; i += 256) wlds[i] = w[i];
    __syncthreads();
    if (tid < 81) {
        int j = tid / 9, k = tid % 9;
        float acc = 0.f;
#pragma unroll 8
        for (int c = 0; c < CH; ++c) acc = fmaf(wlds[c*9 + j], wlds[c*9 + k], acc);
        Ml[tid] = acc;
    } else if (tid < 90) {
        int k = tid - 81;
        float acc = 0.f;
#pragma unroll 8
        for (int c = 0; c < CH; ++c) acc += wlds[c*9 + k];
        Wl[k] = acc;
    }
    __syncthreads();

    int fq = tid & 15;
    int tr = tid >> 4;
    int gt = blockIdx.x * 16 + tr;          // b*2048 + t
    int t = gt & (TT_OUT - 1);
    int b = gt >> 11;
    const float* xb = x + (size_t)b * (X_H * X_W);

    float xr[3][9];
    int r0 = 2*t - 1;
#pragma unroll
    for (int kh = 0; kh < 3; ++kh) {
        int r = r0 + kh;
        if (r >= 0 && r < X_H) {
            const float* rp = xb + (size_t)r * X_W + 8*fq;
            f4 v0 = *(const f4*)rp;
            f4 v1 = *(const f4*)(rp + 4);
            xr[kh][0]=v0.x; xr[kh][1]=v0.y; xr[kh][2]=v0.z; xr[kh][3]=v0.w;
            xr[kh][4]=v1.x; xr[kh][5]=v1.y; xr[kh][6]=v1.z; xr[kh][7]=v1.w;
            xr[kh][8] = (fq == 15) ? 0.f : rp[8];
        } else {
#pragma unroll
            for (int k = 0; k < 9; ++k) xr[kh][k] = 0.f;
        }
    }

    float s1 = 0.f, ss = 0.f;
#pragma unroll
    for (int jf = 0; jf < 4; ++jf) {
        float tv[9];
#pragma unroll
        for (int kh = 0; kh < 3; ++kh)
#pragma unroll
            for (int kw = 0; kw < 3; ++kw)
                tv[kh*3+kw] = xr[kh][2*jf + kw];
#pragma unroll
        for (int k = 0; k < 9; ++k) s1 = fmaf(Wl[k], tv[k], s1);
#pragma unroll
        for (int j = 0; j < 9; ++j) {
            float tj = 0.f;
#pragma unroll
            for (int k = 0; k < 9; ++k) tj = fmaf(Ml[j*9+k], tv[k], tj);
            ss = fmaf(tv[j], tj, ss);
        }
    }
#pragma unroll
    for (int off = 1; off < 16; off <<= 1) {
        s1 += __shfl_xor(s1, off);
        ss += __shfl_xor(ss, off);
    }
    if (fq == 0) {
        ws[S1_OFF + gt] = s1;
        ws[SS_OFF + gt] = ss;
    }
}

// ---------------- kernel 2: cumulative scan -> {mu, istd}, float ----------
__global__ __launch_bounds__(256) void scan_kernel(float* __restrict__ ws) {
    int b = blockIdx.x;
    int tid = threadIdx.x;
    int lane = tid & 63;
    int wv = tid >> 6;
    const f4* S1v = (const f4*)(ws + S1_OFF + b*TT_OUT);
    const f4* SSv = (const f4*)(ws + SS_OFF + b*TT_OUT);
    f2* MI = (f2*)(ws + MI_OFF) + b*TT_OUT;
    __shared__ float wsum_lds[4];

    f4 a0 = S1v[tid*2], a1 = S1v[tid*2+1];
    f4 b0 = SSv[tid*2], b1 = SSv[tid*2+1];
    float s1loc[8] = {a0.x,a0.y,a0.z,a0.w,a1.x,a1.y,a1.z,a1.w};
    float ssloc[8] = {b0.x,b0.y,b0.z,b0.w,b1.x,b1.y,b1.z,b1.w};

    float v[8];
    float tot = 0.f;
#pragma unroll
    for (int i = 0; i < 8; ++i) { tot += s1loc[i]; v[i] = tot; }
    float incl = tot;
#pragma unroll
    for (int off = 1; off < 64; off <<= 1) {
        float n = __shfl_up(incl, off);
        if (lane >= off) incl += n;
    }
    if (lane == 63) wsum_lds[wv] = incl;
    __syncthreads();
    float woff = 0.f;
    for (int w2 = 0; w2 < wv; ++w2) woff += wsum_lds[w2];
    float prefix = woff + incl - tot;

    float muloc[8], v2[8];
    float tot2 = 0.f;
#pragma unroll
    for (int i = 0; i < 8; ++i) {
        int t = tid*8 + i;
        float cs = prefix + v[i];
        float cnt = (float)(t+1) * 8192.f;
        float mu = cs / cnt;
        float sq = ssloc[i] - 2.f*mu*s1loc[i] + 8192.f*mu*mu;
        muloc[i] = mu;
        tot2 += sq; v2[i] = tot2;
    }
    float incl2 = tot2;
#pragma unroll
    for (int off = 1; off < 64; off <<= 1) {
        float n = __shfl_up(incl2, off);
        if (lane >= off) incl2 += n;
    }
    __syncthreads();
    if (lane == 63) wsum_lds[wv] = incl2;
    __syncthreads();
    float woff2 = 0.f;
    for (int w2 = 0; w2 < wv; ++w2) woff2 += wsum_lds[w2];
    float prefix2 = woff2 + incl2 - tot2;
#pragma unroll
    for (int i = 0; i < 8; ++i) {
        int t = tid*8 + i;
        float cnt = (float)(t+1) * 8192.f;
        float var = (prefix2 + v2[i]) / cnt;
        f2 mi;
        mi.x = muloc[i];
        mi.y = rsqrtf(var + EPS_GN);
        MI[t] = mi;
    }
}

// ---------------- kernel 3: conv via f16 dot2 + norm + relu, f4 nt stores --
#define T_TILE 16
#define CG 32
__global__ __launch_bounds__(256) void out_kernel(const float* __restrict__ x,
        const float* __restrict__ w, const float* __restrict__ scale,
        const float* __restrict__ ws, float* __restrict__ out) {
    __shared__ h2 wp[CG][5];      // packed (w*scale) pairs: k={01,23,45,67,8_}
    __shared__ float slv[CG];
    int tid = threadIdx.x;
    int b = blockIdx.z;
    int c0 = blockIdx.y * CG;
    int t0 = blockIdx.x * T_TILE;
    if (tid < CG*5) {
        int c = tid / 5, p = tid % 5;
        float sc = scale[c0 + c];
        int k0 = 2*p, k1 = 2*p + 1;
        float w0 = w[(c0 + c)*9 + k0] * sc;
        float w1 = (k1 < 9) ? w[(c0 + c)*9 + k1] * sc : 0.f;
        h2 hv; hv.x = (_Float16)w0; hv.y = (_Float16)w1;
        wp[c][p] = hv;
    }
    if (tid < CG) slv[tid] = scale[c0 + tid];
    __syncthreads();

    int fq = tid & 15;          // 4 f's: f = 4*fq .. 4*fq+3
    int tr = tid >> 4;          // 0..15
    int t = t0 + tr;
    const float* xb = x + (size_t)b * (X_H * X_W);
    f2 mi = ((const f2*)(ws + MI_OFF))[b*TT_OUT + t];
    float mu = mi.x, istd = mi.y;
    float nb_base = -mu * istd;

    float xr[3][9];
    int r0 = 2*t - 1;
#pragma unroll
    for (int kh = 0; kh < 3; ++kh) {
        int r = r0 + kh;
        if (r >= 0 && r < X_H) {
            const float* rp = xb + (size_t)r * X_W + 8*fq;
            f4 v0 = *(const f4*)rp;
            f4 v1 = *(const f4*)(rp + 4);
            xr[kh][0]=v0.x; xr[kh][1]=v0.y; xr[kh][2]=v0.z; xr[kh][3]=v0.w;
            xr[kh][4]=v1.x; xr[kh][5]=v1.y; xr[kh][6]=v1.z; xr[kh][7]=v1.w;
            xr[kh][8] = (fq == 15) ? 0.f : rp[8];
        } else {
#pragma unroll
            for (int k = 0; k < 9; ++k) xr[kh][k] = 0.f;
        }
    }

    // pack patch taps to f16 pairs per output position jf
    h2 pk[4][5];
#pragma unroll
    for (int jf = 0; jf < 4; ++jf) {
#pragma unroll
        for (int p = 0; p < 4; ++p) {
            int k0 = 2*p, k1 = 2*p + 1;
            h2 hv;
            hv.x = (_Float16)xr[k0/3][2*jf + k0%3];
            hv.y = (_Float16)xr[k1/3][2*jf + k1%3];
            pk[jf][p] = hv;
        }
        h2 hv; hv.x = (_Float16)xr[2][2*jf + 2]; hv.y = (_Float16)0.f;
        pk[jf][4] = hv;
    }

    float* ob = out + (((size_t)(b*CH + c0) * TT_OUT + t) * FF + 4*fq);
#pragma unroll
    for (int c = 0; c < CG; ++c) {
        h2 q0 = wp[c][0], q1 = wp[c][1], q2 = wp[c][2], q3 = wp[c][3], q4 = wp[c][4];
        float nb = nb_base * slv[c];
        f4 v;
#pragma unroll
        for (int jf = 0; jf < 4; ++jf) {
            float h = DOT2(pk[jf][4], q4, 0.f);
            h = DOT2(pk[jf][0], q0, h);
            h = DOT2(pk[jf][1], q1, h);
            h = DOT2(pk[jf][2], q2, h);
            h = DOT2(pk[jf][3], q3, h);
            v[jf] = fmaxf(fmaf(h, istd, nb), 0.f);
        }
        __builtin_nontemporal_store(v, (f4*)(ob + (size_t)c * (TT_OUT * FF)));
    }
}

extern "C" void kernel_launch(void* const* d_in, const int* in_sizes, int n_in,
                              void* d_out, int out_size, void* d_ws, size_t ws_size,
                              hipStream_t stream) {
    const float* x     = (const float*)d_in[0];
    const float* w     = (const float*)d_in[1];
    const float* scale = (const float*)d_in[2];
    float* out = (float*)d_out;
    float* ws  = (float*)d_ws;

    stats_kernel<<<(BATCH*TT_OUT)/16, 256, 0, stream>>>(x, w, ws);
    scan_kernel<<<BATCH, 256, 0, stream>>>(ws);
    out_kernel<<<dim3(TT_OUT/T_TILE, CH/CG, BATCH), 256, 0, stream>>>(x, w, scale, ws, out);
}

// Round 7
// 59.350 us; speedup vs baseline: 1.1053x; 1.0894x over previous
//
#include <hip/hip_runtime.h>

#define X_H 4096
#define X_W 128
#define BATCH 4
#define CH 128
#define TT_OUT 2048
#define FF 64
#define EPS_GN 1e-3f

typedef float f4 __attribute__((ext_vector_type(4)));

// workspace float offsets
#define S1_OFF 0
#define SS_OFF (BATCH*TT_OUT)

// ---------------- kernel 1: per-(b,t) S1, SS (prep fused via LDS) ----------
__global__ __launch_bounds__(256) void stats_kernel(const float* __restrict__ x,
                                                    const float* __restrict__ w,
                                                    float* __restrict__ ws) {
    __shared__ float wlds[CH*9];
    __shared__ float Ml[81];
    __shared__ float Wl[9];
    int tid = threadIdx.x;
#pragma unroll
    for (int i = tid; i < CH*9; i += 256) wlds[i] = w[i];
    __syncthreads();
    if (tid < 81) {
        int j = tid / 9, k = tid % 9;
        float acc = 0.f;
#pragma unroll 8
        for (int c = 0; c < CH; ++c) acc = fmaf(wlds[c*9 + j], wlds[c*9 + k], acc);
        Ml[tid] = acc;
    } else if (tid < 90) {
        int k = tid - 81;
        float acc = 0.f;
#pragma unroll 8
        for (int c = 0; c < CH; ++c) acc += wlds[c*9 + k];
        Wl[k] = acc;
    }
    __syncthreads();

    int fq = tid & 15;
    int tr = tid >> 4;
    int gt = blockIdx.x * 16 + tr;          // b*2048 + t
    int t = gt & (TT_OUT - 1);
    int b = gt >> 11;
    const float* xb = x + (size_t)b * (X_H * X_W);

    float xr[3][9];
    int r0 = 2*t - 1;
#pragma unroll
    for (int kh = 0; kh < 3; ++kh) {
        int r = r0 + kh;
        if (r >= 0 && r < X_H) {
            const float* rp = xb + (size_t)r * X_W + 8*fq;
            f4 v0 = *(const f4*)rp;
            f4 v1 = *(const f4*)(rp + 4);
            xr[kh][0]=v0.x; xr[kh][1]=v0.y; xr[kh][2]=v0.z; xr[kh][3]=v0.w;
            xr[kh][4]=v1.x; xr[kh][5]=v1.y; xr[kh][6]=v1.z; xr[kh][7]=v1.w;
            xr[kh][8] = (fq == 15) ? 0.f : rp[8];
        } else {
#pragma unroll
            for (int k = 0; k < 9; ++k) xr[kh][k] = 0.f;
        }
    }

    float s1 = 0.f, ss = 0.f;
#pragma unroll
    for (int jf = 0; jf < 4; ++jf) {
        float tv[9];
#pragma unroll
        for (int kh = 0; kh < 3; ++kh)
#pragma unroll
            for (int kw = 0; kw < 3; ++kw)
                tv[kh*3+kw] = xr[kh][2*jf + kw];
#pragma unroll
        for (int k = 0; k < 9; ++k) s1 = fmaf(Wl[k], tv[k], s1);
#pragma unroll
        for (int j = 0; j < 9; ++j) {
            float tj = 0.f;
#pragma unroll
            for (int k = 0; k < 9; ++k) tj = fmaf(Ml[j*9+k], tv[k], tj);
            ss = fmaf(tv[j], tj, ss);
        }
    }
#pragma unroll
    for (int off = 1; off < 16; off <<= 1) {
        s1 += __shfl_xor(s1, off);
        ss += __shfl_xor(ss, off);
    }
    if (fq == 0) {
        ws[S1_OFF + gt] = s1;
        ws[SS_OFF + gt] = ss;
    }
}

// ------- kernel 2: in-block cumulative stats + conv + norm + relu ---------
#define T_TILE 16
#define CG 32
__global__ __launch_bounds__(256) void out_kernel(const float* __restrict__ x,
        const float* __restrict__ w, const float* __restrict__ scale,
        const float* __restrict__ ws, float* __restrict__ out) {
    __shared__ float wl[CG][9];
    __shared__ float sl[CG];
    __shared__ float redA[4], redB[4], redC[4];
    int tid = threadIdx.x;
    int lane = tid & 63;
    int wv = tid >> 6;
    int b = blockIdx.z;
    int c0 = blockIdx.y * CG;
    int t0 = blockIdx.x * T_TILE;

    for (int i = tid; i < CG*9; i += 256) wl[i/9][i%9] = w[c0*9 + i];
    if (tid < CG) sl[tid] = scale[c0 + tid];

    // ---- recompute cumulative prefix over [0, t0) from S1/SS ----
    const float* S1 = ws + S1_OFF + b*TT_OUT;
    const float* SS = ws + SS_OFF + b*TT_OUT;
    const f4* S1v = (const f4*)S1;
    const f4* SSv = (const f4*)SS;
    f4 a0 = S1v[tid*2], a1 = S1v[tid*2+1];
    f4 e0 = SSv[tid*2], e1 = SSv[tid*2+1];
    float s1l[8] = {a0.x,a0.y,a0.z,a0.w,a1.x,a1.y,a1.z,a1.w};
    float ssl[8] = {e0.x,e0.y,e0.z,e0.w,e1.x,e1.y,e1.z,e1.w};
    int tau0 = tid * 8;
    float s1m[8];
    float tot = 0.f;
#pragma unroll
    for (int i = 0; i < 8; ++i) {
        s1m[i] = (tau0 + i < t0) ? s1l[i] : 0.f;
        tot += s1m[i];
    }
    // wave inclusive scan of tot
    float incl = tot;
#pragma unroll
    for (int off = 1; off < 64; off <<= 1) {
        float n = __shfl_up(incl, off);
        if (lane >= off) incl += n;
    }
    if (lane == 63) redA[wv] = incl;
    __syncthreads();
    float woff = 0.f;
    for (int w2 = 0; w2 < wv; ++w2) woff += redA[w2];
    float prefix = woff + incl - tot;      // exclusive prefix of masked S1

    // per-thread: accumulate sq over its masked taus (needs running mean)
    float run = prefix;
    float sqp = 0.f;
#pragma unroll
    for (int i = 0; i < 8; ++i) {
        if (tau0 + i < t0) {
            run += s1l[i];
            float cnt = (float)(tau0 + i + 1) * 8192.f;
            float mu = run / cnt;
            sqp += ssl[i] - 2.f*mu*s1l[i] + 8192.f*mu*mu;
        }
    }
    // block reduce: base1 = sum(masked S1), base_sq = sum(sqp)
    float r1 = tot, r2 = sqp;
#pragma unroll
    for (int off = 32; off > 0; off >>= 1) {
        r1 += __shfl_xor(r1, off);
        r2 += __shfl_xor(r2, off);
    }
    if (lane == 0) { redB[wv] = r1; redC[wv] = r2; }
    __syncthreads();
    float base1 = redB[0] + redB[1] + redB[2] + redB[3];
    float base_sq = redC[0] + redC[1] + redC[2] + redC[3];

    // ---- serial 16-step tile prefix (uniform loads) ----
    int tr = tid >> 4;
    float run16 = base1, sq16 = base_sq;
    float mu_t = 0.f, istd_t = 0.f;
#pragma unroll
    for (int i = 0; i < T_TILE; ++i) {
        int t = t0 + i;
        float s1t = S1[t];
        float sst = SS[t];
        run16 += s1t;
        float cnt = (float)(t + 1) * 8192.f;
        float mu = run16 / cnt;
        sq16 += sst - 2.f*mu*s1t + 8192.f*mu*mu;
        if (i == tr) { mu_t = mu; istd_t = rsqrtf(sq16 / cnt + EPS_GN); }
    }

    // ---- conv + norm + relu ----
    int fq = tid & 15;          // 4 f's: f = 4*fq .. 4*fq+3
    int t = t0 + tr;
    const float* xb = x + (size_t)b * (X_H * X_W);

    float xr[3][9];
    int r0 = 2*t - 1;
#pragma unroll
    for (int kh = 0; kh < 3; ++kh) {
        int r = r0 + kh;
        if (r >= 0 && r < X_H) {
            const float* rp = xb + (size_t)r * X_W + 8*fq;
            f4 v0 = *(const f4*)rp;
            f4 v1 = *(const f4*)(rp + 4);
            xr[kh][0]=v0.x; xr[kh][1]=v0.y; xr[kh][2]=v0.z; xr[kh][3]=v0.w;
            xr[kh][4]=v1.x; xr[kh][5]=v1.y; xr[kh][6]=v1.z; xr[kh][7]=v1.w;
            xr[kh][8] = (fq == 15) ? 0.f : rp[8];
        } else {
#pragma unroll
            for (int k = 0; k < 9; ++k) xr[kh][k] = 0.f;
        }
    }

    float* ob = out + (((size_t)(b*CH + c0) * TT_OUT + t) * FF + 4*fq);
#pragma unroll
    for (int c = 0; c < CG; ++c) {
        float a  = istd_t * sl[c];
        float nb = -mu_t * a;
        f4 v;
#pragma unroll
        for (int jf = 0; jf < 4; ++jf) {
            float h = 0.f;
#pragma unroll
            for (int kh = 0; kh < 3; ++kh)
#pragma unroll
                for (int kw = 0; kw < 3; ++kw)
                    h = fmaf(wl[c][kh*3+kw], xr[kh][2*jf + kw], h);
            v[jf] = fmaxf(fmaf(h, a, nb), 0.f);
        }
        *(f4*)(ob + (size_t)c * (TT_OUT * FF)) = v;
    }
}

extern "C" void kernel_launch(void* const* d_in, const int* in_sizes, int n_in,
                              void* d_out, int out_size, void* d_ws, size_t ws_size,
                              hipStream_t stream) {
    const float* x     = (const float*)d_in[0];
    const float* w     = (const float*)d_in[1];
    const float* scale = (const float*)d_in[2];
    float* out = (float*)d_out;
    float* ws  = (float*)d_ws;

    stats_kernel<<<(BATCH*TT_OUT)/16, 256, 0, stream>>>(x, w, ws);
    out_kernel<<<dim3(TT_OUT/T_TILE, CH/CG, BATCH), 256, 0, stream>>>(x, w, scale, ws, out);
}